// Round 10
// baseline (238.422 us; speedup 1.0000x reference)
//
#include <hip/hip_runtime.h>
#include <stdint.h>

typedef int   v4i __attribute__((ext_vector_type(4)));
typedef float v4f __attribute__((ext_vector_type(4)));

// xt layout: [n][hp=58][wp=66][ci=128] int8, zero-padded (hp-1,wp-1 are src coords)
#define XT_H_STRIDE (66*128)          // 8448
#define XT_N_STRIDE (58*66*128)       // 489984
#define XT_BYTES    (32*58*66*128)    // 15,679,488
#define WQ_BYTES    (256*1152)        // 294,912

__device__ __forceinline__ void gload16(const void* g, void* l) {
  __builtin_amdgcn_global_load_lds(
      (const __attribute__((address_space(1))) void*)g,
      (__attribute__((address_space(3))) void*)l, 16, 0, 0);
}

// ---------------- x transform: fp32 NCHW -> int8 [n][hp][wp][ci] ----------------
// Coalesced both sides via LDS transpose. Unchanged (proven).
__global__ __launch_bounds__(256) void xform_x(const float* __restrict__ x,
                                               char* __restrict__ xt) {
  __shared__ int LB[56 * 33];          // [w][32 ci-dwords + 1 pad]
  int bid = blockIdx.x;                // 32*58
  int n  = bid / 58;
  int hp = bid - n * 58;
  int t  = threadIdx.x;
  int srch = hp - 1;
  bool rowok = (srch >= 0) && (srch < 56);
  char* dstrow = xt + (size_t)n * XT_N_STRIDE + (size_t)hp * XT_H_STRIDE;

  if (rowok) {
    const float* rb = x + ((size_t)(n * 128) * 56 + srch) * 56;   // + ci*3136 + w
#pragma unroll
    for (int u0 = 0; u0 < 2; ++u0) {
      int u  = t + u0 * 256;
      int wb = u & 15;
      int cb = u >> 4;
      int w0 = wb * 4, ci0 = cb * 4;
      if (w0 < 56) {
        int dw[4] = {0, 0, 0, 0};
#pragma unroll
        for (int i = 0; i < 4; ++i) {
          v4f f = *(const v4f*)(rb + (size_t)(ci0 + i) * 3136 + w0);
#pragma unroll
          for (int j = 0; j < 4; ++j)
            dw[j] |= (((int)f[j]) & 255) << (8 * i);
        }
#pragma unroll
        for (int j = 0; j < 4; ++j)
          LB[(w0 + j) * 33 + cb] = dw[j];
      }
    }
    __syncthreads();
    for (int c = t; c < 528; c += 256) {
      int wp  = c >> 3;
      int cio = c & 7;
      int srw = wp - 1;
      v4i v = {0, 0, 0, 0};
      if (srw >= 0 && srw < 56) {
#pragma unroll
        for (int k = 0; k < 4; ++k) v[k] = LB[srw * 33 + cio * 4 + k];
      }
      *(v4i*)(dstrow + c * 16) = v;
    }
  } else {
    v4i z = {0, 0, 0, 0};
    for (int c = t; c < 528; c += 256) *(v4i*)(dstrow + c * 16) = z;
  }
}

// ---------------- w transform: OIHW fp32 -> int8 wq2[kt18][co256][64]; + scale ----------------
// R5 layout (validated): per kt (= tap g * 2 + ci-half) the 256co x 64ci panel
// is contiguous; the GEMM reads A frags directly from this (L2-resident 288KB,
// each frag = 1KB fully-contiguous wave read).
__global__ __launch_bounds__(256) void xform_w(const float* __restrict__ wsrc,
                                               const int* __restrict__ Aq,
                                               const int* __restrict__ Nq,
                                               char* __restrict__ wq2,
                                               float* __restrict__ scale) {
  int idx = blockIdx.x * 256 + threadIdx.x;    // 294912
  int co = idx / 1152;
  int k  = idx - co * 1152;          // K index: g*128 + ci
  int g  = k >> 7;
  int ci = k & 127;
  int kh = g / 3;
  int kw = g - 3 * kh;
  float f = wsrc[(size_t)(co * 128 + ci) * 9 + kh * 3 + kw];
  wq2[((k >> 6) * 256 + co) * 64 + (k & 63)] = (signed char)(int)f;
  if (idx < 256) {
    scale[idx] = (float)Aq[idx] * exp2f(-(float)Nq[idx]);   // exact: A < 2^15
  }
}

// ---------------- GEMM: C[co][n,h,w] = sum_k wq[co][k] * xt[...] ----------------
// R13: ALL-GLOBAL, ZERO-LDS, ZERO-BARRIER.
//   Seven structures (R5..R12: LDS-dbuf / global-reg / reg-dbuf / fenced /
//   DMA-ring / 4-phase / occupancy-doubled) all plateau 57-67us with every
//   pipe <=30%. Shared invariant: an LDS staging pipeline with per-window
//   block-wide barriers (64KB DMA-write + 128KB frag-read per CU-kt through
//   the LDS pipe, serialized against barrier convoys). This round removes
//   the invariant: both operands are cache-resident (wq2 288KB L2-hot; xt
//   B-frags 64B-per-4-lane coalesced, wm-pair waves read IDENTICAL B bytes
//   -> L1 hits; wn-pairs share A), so frags are loaded straight from global
//   into registers. Pure dataflow k-loop: 8 loads + 16 MFMA, no barriers,
//   no waitcnt discipline; #pragma unroll 1 stops full-unroll load hoisting.
//   4 waves/SIMD (VGPR ~110 <= 128 via __launch_bounds__(256,4)) hide latency.
//   B bytes/lane-mapping identical to R5's validated Bp path; A layout R5.
// 128x128 tile, 4 waves (2x2), 4x4 frags of mfma_i32_16x16x64_i8, BK=64.
// Grid 1792 (R5 mt/nt XCD swizzle). LDS 0.
__global__ __launch_bounds__(256, 4) void qconv_gemm(
    const char* __restrict__ xt, const char* __restrict__ wq2,
    const float* __restrict__ bias, const float* __restrict__ scale,
    const int* __restrict__ pmin, const int* __restrict__ pmax,
    float* __restrict__ out) {
  // XCD-aware swizzle: mt pair (shared xt rows) + contiguous nt range per XCD.
  int bid = blockIdx.x;        // 1792
  int xcd = bid & 7;
  int q   = bid >> 3;
  int mt  = q & 1;
  int nt  = xcd * 112 + (q >> 1);
  int n   = nt / 28;
  int ht  = nt - n * 28;
  int h0  = ht * 2;
  int m0  = mt * 128;

  int t  = threadIdx.x;
  int wv = t >> 6;
  int ln = t & 63;
  int quad = ln >> 4;
  int l16  = ln & 15;
  int wm = wv & 1, wn = wv >> 1;

  const char* xb = xt + (size_t)n * XT_N_STRIDE + (size_t)h0 * XT_H_STRIDE;
  // A lane addr (mfma_i32_16x16x64_i8 A: lane l holds row l&15, k=(l>>4)*16..+16):
  // row = m0 + wm*64 + i*16 + l16 -> frag i at +i*1024; wave read = 1KB contiguous.
  const char* abase = wq2 + (size_t)(m0 + wm * 64 + l16) * 64 + quad * 16;
  // B lane addr: spatial sl = wn*64 + j*16 + l16 (w = j*16+l16, dh = wn);
  // ci = p*64 + quad*16 + t. Same bytes R5's Bp staging fetched (validated).
  const char* bbase = xb + wn * XT_H_STRIDE + l16 * 128 + quad * 16;

  v4i acc[4][4];
#pragma unroll
  for (int i = 0; i < 4; ++i)
#pragma unroll
    for (int j = 0; j < 4; ++j) {
      v4i z = {0, 0, 0, 0};
      acc[i][j] = z;
    }

#pragma unroll 1
  for (int kt = 0; kt < 18; ++kt) {
    int p  = kt & 1;                   // ci-half within the tap
    int g  = kt >> 1;                  // spatial tap 0..8
    int kh = g / 3;                    // compiler: magic-mul
    int kw = g - 3 * kh;

    const char* ak = abase + (size_t)kt * 16384;
    const char* bk = bbase + kh * XT_H_STRIDE + kw * 128 + p * 64;

    v4i a[4], b[4];
#pragma unroll
    for (int i = 0; i < 4; ++i)
      a[i] = *(const v4i*)(ak + i * 1024);
#pragma unroll
    for (int j = 0; j < 4; ++j)
      b[j] = *(const v4i*)(bk + j * 2048);

#pragma unroll
    for (int i = 0; i < 4; ++i)
#pragma unroll
      for (int j = 0; j < 4; ++j)
        acc[i][j] = __builtin_amdgcn_mfma_i32_16x16x64_i8(a[i], b[j], acc[i][j], 0, 0, 0);
  }

  // epilogue (R5-validated mapping): co = m0 + wm*64 + i*16 + quad*4 + r ;
  // spatial sl = wn*64 + j*16 + l16 -> w = sl&63, dh = sl>>6. float4 bias/scale.
  float mn = (float)pmin[0];
  float mx = (float)pmax[0];
#pragma unroll
  for (int i = 0; i < 4; ++i) {
    int co_b = m0 + wm * 64 + i * 16 + quad * 4;
    v4f bs4 = *(const v4f*)(bias + co_b);
    v4f sc4 = *(const v4f*)(scale + co_b);
#pragma unroll
    for (int r = 0; r < 4; ++r) {
      int co = co_b + r;
      float bs = bs4[r];
      float sc = sc4[r];
#pragma unroll
      for (int j = 0; j < 4; ++j) {
        int sl = wn * 64 + j * 16 + l16;
        int w  = sl & 63;
        int dh = sl >> 6;
        if (w < 56) {
          float f = (float)acc[i][j][r] + bs;
          f = rintf(f * sc);                 // half-to-even, matches np.round
          f = fminf(fmaxf(f, mn), mx);
          out[(((size_t)n * 256 + co) * 56 + (h0 + dh)) * 56 + w] = f;
        }
      }
    }
  }
}

extern "C" void kernel_launch(void* const* d_in, const int* in_sizes, int n_in,
                              void* d_out, int out_size, void* d_ws, size_t ws_size,
                              hipStream_t stream) {
  const float* x  = (const float*)d_in[0];
  const float* w  = (const float*)d_in[1];
  const float* b  = (const float*)d_in[2];
  const int*   Aq = (const int*)d_in[3];
  const int*   Nq = (const int*)d_in[4];
  const int*   mn = (const int*)d_in[5];
  const int*   mx = (const int*)d_in[6];
  float* out = (float*)d_out;

  char*  xt    = (char*)d_ws;                  // 15,679,488 B
  char*  wq2   = xt + XT_BYTES;                // 294,912 B (kt18 tile layout)
  float* scale = (float*)(wq2 + WQ_BYTES);     // 1 KiB

  hipLaunchKernelGGL(xform_x, dim3(32 * 58), dim3(256), 0, stream, x, xt);
  hipLaunchKernelGGL(xform_w, dim3(1152), dim3(256), 0, stream, w, Aq, Nq, wq2, scale);
  hipLaunchKernelGGL(qconv_gemm, dim3(1792), dim3(256), 0, stream,
                     xt, wq2, b, scale, mn, mx, out);
}

// Round 11
// 198.654 us; speedup vs baseline: 1.2002x; 1.2002x over previous
//
#include <hip/hip_runtime.h>
#include <stdint.h>

typedef int   v4i __attribute__((ext_vector_type(4)));
typedef float v4f __attribute__((ext_vector_type(4)));

// xt layout: [n][hp=58][wp=66][ci=128] int8, zero-padded (hp-1,wp-1 are src coords)
#define XT_H_STRIDE (66*128)          // 8448
#define XT_N_STRIDE (58*66*128)       // 489984
#define XT_BYTES    (32*58*66*128)    // 15,679,488
#define WQ_BYTES    (256*1152)        // 294,912

__device__ __forceinline__ void gload16(const void* g, void* l) {
  __builtin_amdgcn_global_load_lds(
      (const __attribute__((address_space(1))) void*)g,
      (__attribute__((address_space(3))) void*)l, 16, 0, 0);
}

// ---------------- x transform: fp32 NCHW -> int8 [n][hp][wp][ci] ----------------
// Coalesced both sides via LDS transpose. Unchanged (proven).
__global__ __launch_bounds__(256) void xform_x(const float* __restrict__ x,
                                               char* __restrict__ xt) {
  __shared__ int LB[56 * 33];          // [w][32 ci-dwords + 1 pad]
  int bid = blockIdx.x;                // 32*58
  int n  = bid / 58;
  int hp = bid - n * 58;
  int t  = threadIdx.x;
  int srch = hp - 1;
  bool rowok = (srch >= 0) && (srch < 56);
  char* dstrow = xt + (size_t)n * XT_N_STRIDE + (size_t)hp * XT_H_STRIDE;

  if (rowok) {
    const float* rb = x + ((size_t)(n * 128) * 56 + srch) * 56;   // + ci*3136 + w
#pragma unroll
    for (int u0 = 0; u0 < 2; ++u0) {
      int u  = t + u0 * 256;
      int wb = u & 15;
      int cb = u >> 4;
      int w0 = wb * 4, ci0 = cb * 4;
      if (w0 < 56) {
        int dw[4] = {0, 0, 0, 0};
#pragma unroll
        for (int i = 0; i < 4; ++i) {
          v4f f = *(const v4f*)(rb + (size_t)(ci0 + i) * 3136 + w0);
#pragma unroll
          for (int j = 0; j < 4; ++j)
            dw[j] |= (((int)f[j]) & 255) << (8 * i);
        }
#pragma unroll
        for (int j = 0; j < 4; ++j)
          LB[(w0 + j) * 33 + cb] = dw[j];
      }
    }
    __syncthreads();
    for (int c = t; c < 528; c += 256) {
      int wp  = c >> 3;
      int cio = c & 7;
      int srw = wp - 1;
      v4i v = {0, 0, 0, 0};
      if (srw >= 0 && srw < 56) {
#pragma unroll
        for (int k = 0; k < 4; ++k) v[k] = LB[srw * 33 + cio * 4 + k];
      }
      *(v4i*)(dstrow + c * 16) = v;
    }
  } else {
    v4i z = {0, 0, 0, 0};
    for (int c = t; c < 528; c += 256) *(v4i*)(dstrow + c * 16) = z;
  }
}

// ---------------- w transform: OIHW fp32 -> int8 wq2[kt18][co256][64]; + scale ----------------
// R5 layout (validated): per kt the 256co x 64ci panel is contiguous; the GEMM
// reads A frags directly from this (288KB, L2-resident) as 1KB-contiguous wave
// loads, register-double-buffered under explicit fences.
__global__ __launch_bounds__(256) void xform_w(const float* __restrict__ wsrc,
                                               const int* __restrict__ Aq,
                                               const int* __restrict__ Nq,
                                               char* __restrict__ wq2,
                                               float* __restrict__ scale) {
  int idx = blockIdx.x * 256 + threadIdx.x;    // 294912
  int co = idx / 1152;
  int k  = idx - co * 1152;          // K index: g*128 + ci
  int g  = k >> 7;
  int ci = k & 127;
  int kh = g / 3;
  int kw = g - 3 * kh;
  float f = wsrc[(size_t)(co * 128 + ci) * 9 + kh * 3 + kw];
  wq2[((k >> 6) * 256 + co) * 64 + (k & 63)] = (signed char)(int)f;
  if (idx < 256) {
    scale[idx] = (float)Aq[idx] * exp2f(-(float)Nq[idx]);   // exact: A < 2^15
  }
}

// ---------------- GEMM: C[co][n,h,w] = sum_k wq[co][k] * xt[...] ----------------
// R14: cut the LDS pipe in half + zero-conflict B + fenced register A.
//   Calibrated model (R8 60us@2blk-LDS, R12 57us@4blk-LDS, R13 105us@global):
//   binding resource = the single per-CU LDS pipe (R12: ~2500cy/window of
//   reads+writes incl. a 4-way B-read conflict vs MFMA 1307cy). R13 proved
//   occupancy/TLP is NOT the constraint (38.7% occ, 105us) and that per-wave
//   global frag reads choke L1. So: A never touches LDS (register loads from
//   L2-hot wq2, pinned between asm fences w/ exact counted vmcnt -- the fix
//   R5/R6 lacked); B staged per TAP (2 windows) in R8's PROVEN zero-conflict
//   8-slot-XOR 128B-row layout, double-buffered; 2 barriers per tap (18 vs 36).
//   Per CU-tap @3 blocks: MFMA 1960cy > LDS ~1550 > L1-A ~1540 -> MFMA-bound.
// vmcnt ledger (per wave, per tap g): carry-in {B(g):5, A(g,0):4}; issue
//   an=A(g,1)[4] then B(g+1)[5]; vmcnt(9) drains carry-in; barrier; p0 MFMA;
//   issue af2=A(g+1,0)[4]; vmcnt(9) drains an... wait order [an,B,af2] ->
//   vmcnt(9) leaves {B(g+1),af2}=9, drains an. p1 MFMA; af=af2; barrier(WAR).
//   g=8 tails: vmcnt(4) / vmcnt(0).
// 128x128 tile, 4 waves (2x2), 4x4 frags mfma_i32_16x16x64_i8 (R5-validated).
// LDS: Bs[2][16896]=33792. VGPR ~145 -> __launch_bounds__(256,3), 3 blocks/CU.
// Grid 1792 (R12 mt/nt XCD swizzle).
__global__ __launch_bounds__(256, 3) void qconv_gemm(
    const char* __restrict__ xt, const char* __restrict__ wq2,
    const float* __restrict__ bias, const float* __restrict__ scale,
    const int* __restrict__ pmin, const int* __restrict__ pmax,
    float* __restrict__ out) {
  __shared__ __align__(16) char Bs[2][16896];   // per-tap: 2 rows x 528 slots x 16B

  int bid = blockIdx.x;        // 1792
  int xcd = bid & 7;
  int q   = bid >> 3;
  int mt  = q & 1;
  int nt  = xcd * 112 + (q >> 1);
  int n   = nt / 28;
  int ht  = nt - n * 28;
  int h0  = ht * 2;
  int m0  = mt * 128;

  int t  = threadIdx.x;
  int wv = t >> 6;
  int ln = t & 63;
  int quad = ln >> 4;
  int l16  = ln & 15;
  int wm = wv & 1, wn = wv >> 1;

  const char* xb = xt + (size_t)n * XT_N_STRIDE + (size_t)h0 * XT_H_STRIDE;
  // A lane addr (16x16x64 A layout: lane l = row l&15, k-chunk (l>>4)*16):
  const char* abase = wq2 + (size_t)(m0 + wm * 64 + l16) * 64 + quad * 16;

  // ---- B stage helper values (R8 pattern, 2 rows x 528 slots/tap) ----
  // it 0..3: s = t + it*256 ; tail: lanes ln<8: s = 1024 + wv*8 + ln
  int srow[4], soff[4];
#pragma unroll
  for (int it = 0; it < 4; ++it) {
    int s  = t + it * 256;
    int r  = (s >= 528) ? 1 : 0;
    int rr = s - r * 528;
    int w  = rr >> 3;
    int cq = rr & 7;
    srow[it] = r;
    soff[it] = w * 128 + ((cq ^ (w & 7)) << 4);
  }
  int stl_row, stl_off;
  {
    int s  = 1024 + wv * 8 + ln;       // only ln<8 lanes issue
    int rr = s - 528;                  // row 1 always
    int w  = rr >> 3;
    int cq = rr & 7;
    stl_row = 1;
    stl_off = w * 128 + ((cq ^ (w & 7)) << 4);
  }

#define STAGE_B(gg, buf)                                                        \
  do {                                                                          \
    const char* bsrc = xb + (size_t)((gg) / 3) * XT_H_STRIDE;                   \
    _Pragma("unroll")                                                           \
    for (int it = 0; it < 4; ++it)                                              \
      gload16(bsrc + srow[it] * XT_H_STRIDE + ((gg) % 3) * 128 + soff[it],      \
              Bs[buf] + it * 4096 + wv * 1024);                                 \
    if (ln < 8)                                                                 \
      gload16(bsrc + stl_row * XT_H_STRIDE + ((gg) % 3) * 128 + stl_off,        \
              Bs[buf] + 16384 + wv * 128);                                      \
  } while (0)
  // note: kw shift folded into source (+kw*128) so staged w-index is the
  // READ w-index; reads then use (l16)&7-style XOR with the same w parity.
  // Actually simpler: stage UNSHIFTED rows (kw=0 base) and shift on read --
  // see read addressing below which uses (l16+kw). To keep the R8-proven
  // pairing (slot XOR uses the stored w), we stage unshifted:
#undef STAGE_B
#define STAGE_B(gg, buf)                                                        \
  do {                                                                          \
    const char* bsrc = xb + (size_t)((gg) / 3) * XT_H_STRIDE;                   \
    _Pragma("unroll")                                                           \
    for (int it = 0; it < 4; ++it)                                              \
      gload16(bsrc + srow[it] * XT_H_STRIDE + soff[it],                         \
              Bs[buf] + it * 4096 + wv * 1024);                                 \
    if (ln < 8)                                                                 \
      gload16(bsrc + stl_row * XT_H_STRIDE + stl_off,                           \
              Bs[buf] + 16384 + wv * 128);                                      \
  } while (0)

  // ---- prologue: af = A(0,0) register loads; stage B(0) ----
  v4i af[4], an[4], af2[4], b[4];
#pragma unroll
  for (int i = 0; i < 4; ++i)
    af[i] = *(const v4i*)(abase + i * 1024);
  STAGE_B(0, 0);

  v4i acc[4][4];
#pragma unroll
  for (int i = 0; i < 4; ++i)
#pragma unroll
    for (int j = 0; j < 4; ++j) {
      v4i z = {0, 0, 0, 0};
      acc[i][j] = z;
    }

#pragma unroll 1
  for (int g = 0; g < 9; ++g) {
    const int kh = g / 3;
    const int kw = g - 3 * kh;
    const int bufB = g & 1;

    // WAR barrier: all waves finished reading Bs[bufB^1] (tap g-1)
    asm volatile("s_barrier" ::: "memory");

    // issue an = A(g,1) register loads [4]  (oldest of this tap's issues)
    {
      const char* ak = abase + (size_t)(2 * g + 1) * 16384;
#pragma unroll
      for (int i = 0; i < 4; ++i)
        an[i] = *(const v4i*)(ak + i * 1024);
    }
    // issue B(g+1) DMA [5]
    if (g < 8) STAGE_B(g + 1, bufB ^ 1);

    // drain carry-in {B(g):5, A(g,0):4}; leave {an:4, B(g+1):5}
    if (g < 8) {
      asm volatile("s_waitcnt vmcnt(9)" ::: "memory");
    } else {
      asm volatile("s_waitcnt vmcnt(4)" ::: "memory");   // leave an only
    }
    asm volatile("s_barrier" ::: "memory");              // RAW: B(g) visible

    // ---- p = 0 half: b frags from Bs[bufB], MFMA with af ----
    {
      const char* bb = Bs[bufB] + wn * 8448 + (l16 + kw) * 128;
      int sm = (l16 + kw) & 7;
#pragma unroll
      for (int j = 0; j < 4; ++j)
        b[j] = *(const v4i*)(bb + j * 2048 + ((quad ^ sm) << 4));
#pragma unroll
      for (int i = 0; i < 4; ++i)
#pragma unroll
        for (int j = 0; j < 4; ++j)
          acc[i][j] = __builtin_amdgcn_mfma_i32_16x16x64_i8(af[i], b[j], acc[i][j], 0, 0, 0);
    }

    // issue af2 = A(g+1,0) register loads [4]
    if (g < 8) {
      const char* ak = abase + (size_t)(2 * g + 2) * 16384;
#pragma unroll
      for (int i = 0; i < 4; ++i)
        af2[i] = *(const v4i*)(ak + i * 1024);
      // drain an (oldest 4 of {an:4, B(g+1):5, af2:4}); leave 9
      asm volatile("s_waitcnt vmcnt(9)" ::: "memory");
    } else {
      asm volatile("s_waitcnt vmcnt(0)" ::: "memory");
    }

    // ---- p = 1 half: MFMA with an ----
    {
      const char* bb = Bs[bufB] + wn * 8448 + (l16 + kw) * 128;
      int sm = (l16 + kw) & 7;
#pragma unroll
      for (int j = 0; j < 4; ++j)
        b[j] = *(const v4i*)(bb + j * 2048 + (((4 + quad) ^ sm) << 4));
#pragma unroll
      for (int i = 0; i < 4; ++i)
#pragma unroll
        for (int j = 0; j < 4; ++j)
          acc[i][j] = __builtin_amdgcn_mfma_i32_16x16x64_i8(an[i], b[j], acc[i][j], 0, 0, 0);
    }

    if (g < 8) {
#pragma unroll
      for (int i = 0; i < 4; ++i) af[i] = af2[i];
    }
  }

  // epilogue (R5/R12-validated): co = m0 + wm*64 + i*16 + quad*4 + r ;
  // spatial sl = wn*64 + j*16 + l16 -> w = sl&63, dh = sl>>6
  float mn = (float)pmin[0];
  float mx = (float)pmax[0];
#pragma unroll
  for (int i = 0; i < 4; ++i) {
    int co_b = m0 + wm * 64 + i * 16 + quad * 4;
    v4f bs4 = *(const v4f*)(bias + co_b);
    v4f sc4 = *(const v4f*)(scale + co_b);
#pragma unroll
    for (int r = 0; r < 4; ++r) {
      int co = co_b + r;
      float bs = bs4[r];
      float sc = sc4[r];
#pragma unroll
      for (int j = 0; j < 4; ++j) {
        int sl = wn * 64 + j * 16 + l16;
        int w  = sl & 63;
        int dh = sl >> 6;
        if (w < 56) {
          float f = (float)acc[i][j][r] + bs;
          f = rintf(f * sc);                 // half-to-even, matches np.round
          f = fminf(fmaxf(f, mn), mx);
          out[(((size_t)n * 256 + co) * 56 + (h0 + dh)) * 56 + w] = f;
        }
      }
    }
  }
}

extern "C" void kernel_launch(void* const* d_in, const int* in_sizes, int n_in,
                              void* d_out, int out_size, void* d_ws, size_t ws_size,
                              hipStream_t stream) {
  const float* x  = (const float*)d_in[0];
  const float* w  = (const float*)d_in[1];
  const float* b  = (const float*)d_in[2];
  const int*   Aq = (const int*)d_in[3];
  const int*   Nq = (const int*)d_in[4];
  const int*   mn = (const int*)d_in[5];
  const int*   mx = (const int*)d_in[6];
  float* out = (float*)d_out;

  char*  xt    = (char*)d_ws;                  // 15,679,488 B
  char*  wq2   = xt + XT_BYTES;                // 294,912 B (kt18 tile layout)
  float* scale = (float*)(wq2 + WQ_BYTES);     // 1 KiB

  hipLaunchKernelGGL(xform_x, dim3(32 * 58), dim3(256), 0, stream, x, xt);
  hipLaunchKernelGGL(xform_w, dim3(1152), dim3(256), 0, stream, w, Aq, Nq, wq2, scale);
  hipLaunchKernelGGL(qconv_gemm, dim3(1792), dim3(256), 0, stream,
                     xt, wq2, b, scale, mn, mx, out);
}